// Round 1
// 482.701 us; speedup vs baseline: 1.0298x; 1.0298x over previous
//
#include <hip/hip_runtime.h>
#include <hip/hip_bf16.h>
#include <math.h>

// Problem constants (from reference)
constexpr int Bb   = 32;
constexpr int Ls   = 110;
constexpr int Gs   = 512;
constexpr int Ns   = 40;
constexpr int Ds   = 300;
constexpr int WPc  = 10;
constexpr int WFc  = 10;
constexpr int MAXNc = 110;
constexpr float EPSf  = 1e-8f;
constexpr float CLIPf = 1.0f - 1e-6f;
constexpr int BL = Bb * Ls;        // 3520
constexpr int Mrows = BL * Ns;     // 140800 flattened GEMM rows
constexpr int BPITCH = 328;        // LDS B pitch in shorts
constexpr int KST = 320;           // padded bf16 row stride (shorts), 16B-aligned
constexpr int RGRP = Mrows / 256;  // 550 row-groups of 256

typedef __attribute__((ext_vector_type(8))) short short8_t;
typedef __attribute__((ext_vector_type(4))) short short4_t;
typedef __attribute__((ext_vector_type(4))) float floatx4;

__device__ __forceinline__ unsigned short bf16r(float f) {
  unsigned u = __float_as_uint(f);
  u += 0x7fffu + ((u >> 16) & 1u);          // RNE to bf16
  return (unsigned short)(u >> 16);
}

__device__ __forceinline__ unsigned pkbf(float lo, float hi) {
  unsigned a = __float_as_uint(lo), b = __float_as_uint(hi);
  a += 0x7fffu + ((a >> 16) & 1u);
  b += 0x7fffu + ((b >> 16) & 1u);
  return (a >> 16) | (b & 0xffff0000u);
}

__device__ __forceinline__ short8_t cvt8(const float4 v0, const float4 v1) {
  union { short8_t s; unsigned u[4]; } p;
  p.u[0] = pkbf(v0.x, v0.y);
  p.u[1] = pkbf(v0.z, v0.w);
  p.u[2] = pkbf(v1.x, v1.y);
  p.u[3] = pkbf(v1.z, v1.w);
  return p.s;
}

// ---------------------------------------------------------------------------
// Kernel 0: transpose W_sem (512x512) so the sem GEMM reads it coalesced.
// ---------------------------------------------------------------------------
__global__ __launch_bounds__(256) void transpose_wsem(const float* __restrict__ w,
                                                      float* __restrict__ wt) {
  __shared__ float tile[32][33];
  const int bx = blockIdx.x * 32;
  const int by = blockIdx.y * 32;
  const int tx = threadIdx.x;   // 0..31
  const int ty = threadIdx.y;   // 0..7
#pragma unroll
  for (int r = ty; r < 32; r += 8)
    tile[r][tx] = w[(by + r) * Gs + (bx + tx)];
  __syncthreads();
#pragma unroll
  for (int r = ty; r < 32; r += 8)
    wt[(bx + r) * Gs + (by + tx)] = tile[tx][r];   // wt[t][s] = w[s][t]
}

// ---------------------------------------------------------------------------
// Kernel 0b: WcT[t][s] = bf16(Wc[s][t]), zero-padded to [320][320].
// ---------------------------------------------------------------------------
__global__ __launch_bounds__(256) void wct_prep(const float* __restrict__ wc,
                                                short* __restrict__ wct) {
  __shared__ float tile[32][33];
  const int t0 = blockIdx.x * 32;   // t tile
  const int s0 = blockIdx.y * 32;   // s tile
  const int tx = threadIdx.x, ty = threadIdx.y;
#pragma unroll
  for (int r = ty; r < 32; r += 8) {
    const int s = s0 + r, t = t0 + tx;
    tile[r][tx] = (s < Ds && t < Ds) ? wc[s * Ds + t] : 0.f;
  }
  __syncthreads();
#pragma unroll
  for (int r = ty; r < 32; r += 8) {
    const int t = t0 + r, s = s0 + tx;
    wct[t * KST + s] = (short)bf16r(tile[tx][r]);
  }
}

// ---------------------------------------------------------------------------
// Kernel 0c: kn fp32 -> bf16, zero-padded rows [Mrows][320]; plus fp32-accurate
// per-row inverse norms (so con_attn numerics for n_k are unchanged).
// One wave per row per iteration: lane handles shorts [8*lane, 8*lane+8).
// ---------------------------------------------------------------------------
__global__ __launch_bounds__(256) void kn_prep(const float* __restrict__ kn,
                                               unsigned short* __restrict__ knb,
                                               float* __restrict__ kninv) {
  const int wid = (blockIdx.x * 256 + threadIdx.x) >> 6;
  const int lane = threadIdx.x & 63;
  const int nwaves = gridDim.x * 4;
  for (int row = wid; row < Mrows; row += nwaves) {
    const float* __restrict__ src = kn + (size_t)row * Ds;
    float4 v0 = make_float4(0.f, 0.f, 0.f, 0.f);
    float4 v1 = v0;
    const int d0 = lane * 8;
    if (lane < 37) {                      // d0+7 <= 295 < 300 : full
      v0 = *reinterpret_cast<const float4*>(src + d0);
      v1 = *reinterpret_cast<const float4*>(src + d0 + 4);
    } else if (lane == 37) {              // d 296..299 valid, 300..303 zero
      v0 = *reinterpret_cast<const float4*>(src + d0);
    }
    float ss = v0.x * v0.x + v0.y * v0.y + v0.z * v0.z + v0.w * v0.w +
               v1.x * v1.x + v1.y * v1.y + v1.z * v1.z + v1.w * v1.w;
#pragma unroll
    for (int off = 32; off > 0; off >>= 1) ss += __shfl_xor(ss, off);
    if (lane < 40)
      *reinterpret_cast<short8_t*>(knb + (size_t)row * KST + d0) = cvt8(v0, v1);
    if (lane == 0) kninv[row] = 1.0f / fmaxf(sqrtf(ss), EPSf);
  }
}

// ---------------------------------------------------------------------------
// Kernel 1: att_sem[bl,s] = sum_t W[s,t] * x[bl,t]
// ---------------------------------------------------------------------------
__global__ __launch_bounds__(512) void sem_gemm(const float* __restrict__ nf,
                                                const float* __restrict__ wt,
                                                float* __restrict__ att_sem,
                                                float* __restrict__ na_arr) {
  const int bl0 = blockIdx.x * 8;
  const int s = threadIdx.x;
  const float* __restrict__ x0 = nf + (size_t)bl0 * Gs;
  float acc[8];
#pragma unroll
  for (int r = 0; r < 8; ++r) acc[r] = 0.f;
#pragma unroll 4
  for (int t = 0; t < Gs; ++t) {
    const float wv = wt[t * Gs + s];
#pragma unroll
    for (int r = 0; r < 8; ++r) acc[r] = fmaf(wv, x0[r * Gs + t], acc[r]);
  }
#pragma unroll
  for (int r = 0; r < 8; ++r) att_sem[(size_t)(bl0 + r) * Gs + s] = acc[r];

  __shared__ float partial[8][8];
  const int wave = s >> 6, lane = s & 63;
#pragma unroll
  for (int r = 0; r < 8; ++r) {
    float v = acc[r] * acc[r];
#pragma unroll
    for (int off = 32; off > 0; off >>= 1) v += __shfl_xor(v, off);
    if (lane == 0) partial[r][wave] = v;
  }
  __syncthreads();
  if (s < 8) {
    float sum = 0.f;
#pragma unroll
    for (int w2 = 0; w2 < 8; ++w2) sum += partial[s][w2];
    na_arr[bl0 + s] = fmaxf(sqrtf(sum), EPSf);
  }
}

// ---------------------------------------------------------------------------
// Kernel 2: banded semantic attention + softmax. One block per (b,j).
// Writes the FULL output row (zeros outside window) -> serves as out init.
// ---------------------------------------------------------------------------
__global__ __launch_bounds__(256) void sem_attn(const float* __restrict__ nf,
                                                const float* __restrict__ att_sem,
                                                const float* __restrict__ na_arr,
                                                const int* __restrict__ tlen,
                                                float* __restrict__ out) {
  const int blk = blockIdx.x;
  const int b = blk / Ls, j = blk % Ls;
  const int len = tlen[b];
  float* __restrict__ orow = out + (size_t)(b * Ls + j) * MAXNc;
  if (j >= len) {
    for (int k = threadIdx.x; k < MAXNc; k += 256) orow[k] = 0.f;
    return;
  }
  const int k0 = max(j - WPc, 0);
  const int k1 = min(j + WFc, len - 1);
  const int nk = k1 - k0 + 1;   // <= 21

  __shared__ float xs[Gs];
  __shared__ float sc[21];
  __shared__ float red[4];

  const float* __restrict__ x = nf + (size_t)(b * Ls + j) * Gs;
  float ss = 0.f;
  for (int t = threadIdx.x; t < Gs; t += 256) {
    const float v = x[t];
    xs[t] = v;
    ss += v * v;
  }
  const int wave = threadIdx.x >> 6, lane = threadIdx.x & 63;
#pragma unroll
  for (int off = 32; off > 0; off >>= 1) ss += __shfl_xor(ss, off);
  if (lane == 0) red[wave] = ss;
  __syncthreads();
  const float nfn = fmaxf(sqrtf(red[0] + red[1] + red[2] + red[3]), EPSf);

  for (int i = wave; i < nk; i += 4) {
    const int k = k0 + i;
    const float* __restrict__ as = att_sem + (size_t)(b * Ls + k) * Gs;
    float d = 0.f;
#pragma unroll
    for (int t = lane; t < Gs; t += 64) d = fmaf(xs[t], as[t], d);
#pragma unroll
    for (int off = 32; off > 0; off >>= 1) d += __shfl_xor(d, off);
    if (lane == 0) {
      float cs = d / (nfn * na_arr[b * Ls + k]);
      cs = fminf(fmaxf(cs, -CLIPf), CLIPf);
      sc[i] = 1.0f - acosf(cs) * (float)(1.0 / M_PI);
    }
  }
  __syncthreads();
  if (threadIdx.x == 0) {
    float m = -1e30f;
    for (int i = 0; i < nk; ++i) m = fmaxf(m, sc[i]);
    red[0] = m;
  }
  __syncthreads();
  const float m = red[0];
  if ((int)threadIdx.x < nk) sc[threadIdx.x] = expf(sc[threadIdx.x] - m);
  __syncthreads();
  if (threadIdx.x == 0) {
    float s = 0.f;
    for (int i = 0; i < nk; ++i) s += sc[i];
    red[1] = 1.0f / fmaxf(s, EPSf);
  }
  __syncthreads();
  const float inv = red[1];
  for (int k = threadIdx.x; k < MAXNc; k += 256) {
    float v = 0.f;
    if (k >= k0 && k <= k1) v = 0.5f * sc[k - k0] * inv;
    orow[k] = v;
  }
}

// ---------------------------------------------------------------------------
// Kernel 3: flattened MFMA GEMM  Y[Mrows x 300] = K[Mrows x 300] . Wc[300x300]
// Round-7 structure:
//  - A pre-packed to bf16 [Mrows][320] (kn_prep): 1x16B load/lane/chunk,
//    no in-loop cvt VALU, uniform 10-chunk loop (padding zeros).
//  - chunk-outer / tile-inner: each B LDS fragment reused by 4 row-tiles
//    (ds_reads per wave 200 -> 50; bank-conflict cycles /4).
//  - ring-3 register prefetch of A (depth-2 chunks = 8 loads in flight).
//  - coarse wave-level liveness skip only; inner loop branch-free.
//  - ybar padded to stride 320 (cols 300..319 = 0 via zero B columns).
// ---------------------------------------------------------------------------
__global__ __launch_bounds__(256, 3) void con_gemm_mfma(const unsigned short* __restrict__ knb,
                                                        const short* __restrict__ wct,
                                                        const int* __restrict__ tlen,
                                                        unsigned short* __restrict__ ybar,
                                                        float* __restrict__ rowss) {
  // swizzle decode: xcd = lin%8; partners m=0..3 of group g sit 8 apart
  const int lin = blockIdx.x;
  const int xcd = lin & 7, slot = lin >> 3;
  const int m = slot & 3;
  const int g = xcd + 8 * (slot >> 2);
  if (g >= RGRP) return;
  const int rowbase = g * 256;
  const int n0 = m * 80;

  __shared__ short Bl[80 * BPITCH];   // 52.5 KB
  const int tid = threadIdx.x;
  for (int s = tid; s < 80 * 40; s += 256) {
    const int nl = s / 40, sl = s % 40;
    *reinterpret_cast<short8_t*>(&Bl[nl * BPITCH + sl * 8]) =
        *reinterpret_cast<const short8_t*>(wct + (n0 + nl) * KST + sl * 8);
  }
  __syncthreads();   // the only barrier

  const int wave = tid >> 6, lane = tid & 63;
  const int quad = lane >> 4, l16 = lane & 15;
  const int wrow = rowbase + wave * 64;   // 64 rows per wave

  // wave-level liveness over the 64 rows (span <= 3 bl values)
  {
    bool any = false;
    for (int bl = wrow / Ns; bl <= (wrow + 63) / Ns; ++bl)
      any |= (bl % Ls) < tlen[bl / Ls];
    if (!any) return;   // barrier already passed; safe
  }

  const unsigned short* arow[4];
#pragma unroll
  for (int tt = 0; tt < 4; ++tt)
    arow[tt] = knb + (size_t)(wrow + tt * 16 + l16) * KST + quad * 8;

  floatx4 acc[4][5];
#pragma unroll
  for (int tt = 0; tt < 4; ++tt)
#pragma unroll
    for (int i = 0; i < 5; ++i) acc[tt][i] = (floatx4){0.f, 0.f, 0.f, 0.f};

  // ring-3 A prefetch: preload chunks 0,1; steady state keeps 2 chunks ahead
  short8_t A[3][4];
#pragma unroll
  for (int tt = 0; tt < 4; ++tt) {
    A[0][tt] = *reinterpret_cast<const short8_t*>(arow[tt]);
    A[1][tt] = *reinterpret_cast<const short8_t*>(arow[tt] + 32);
  }

#pragma unroll
  for (int c = 0; c < 10; ++c) {
    if (c < 8) {
#pragma unroll
      for (int tt = 0; tt < 4; ++tt)
        A[(c + 2) % 3][tt] =
            *reinterpret_cast<const short8_t*>(arow[tt] + (c + 2) * 32);
    }
#pragma unroll
    for (int i = 0; i < 5; ++i) {
      const short8_t bfrag = *reinterpret_cast<const short8_t*>(
          &Bl[(i * 16 + l16) * BPITCH + c * 32 + quad * 8]);
#pragma unroll
      for (int tt = 0; tt < 4; ++tt)
        acc[tt][i] = __builtin_amdgcn_mfma_f32_16x16x32_bf16(A[c % 3][tt], bfrag,
                                                             acc[tt][i], 0, 0, 0);
    }
  }

  // epilogue: per-tile liveness guard; partial row-ssq atomics + bf16 store
  // C layout: col = l16 (+16i), row = quad*4 + r
#pragma unroll
  for (int tt = 0; tt < 4; ++tt) {
    const int row0 = wrow + tt * 16;
    const int blA = row0 / Ns, blB = (row0 + 15) / Ns;
    const bool alive = ((blA % Ls) < tlen[blA / Ls]) | ((blB % Ls) < tlen[blB / Ls]);
    if (!alive) continue;
#pragma unroll
    for (int r = 0; r < 4; ++r) {
      float p = 0.f;
#pragma unroll
      for (int i = 0; i < 5; ++i) p = fmaf(acc[tt][i][r], acc[tt][i][r], p);
      p += __shfl_xor(p, 1);
      p += __shfl_xor(p, 2);
      p += __shfl_xor(p, 4);
      p += __shfl_xor(p, 8);
      if (l16 == 0) atomicAdd(&rowss[row0 + quad * 4 + r], p);
    }
#pragma unroll
    for (int i = 0; i < 5; ++i) {
      const int col = n0 + i * 16 + l16;   // < 320 always
#pragma unroll
      for (int r = 0; r < 4; ++r)
        ybar[(size_t)(row0 + quad * 4 + r) * KST + col] = bf16r(acc[tt][i][r]);
    }
  }
}

// ---------------------------------------------------------------------------
// Kernel 4: banded contextual attention via MFMA banded Gram.
// A-side now bf16 from knb (uniform chunks, no cvt, no in-loop ssq);
// k-row inverse norms precomputed (kninv, fp32-accurate).
// ---------------------------------------------------------------------------
__global__ __launch_bounds__(512) void con_attn_mfma(const unsigned short* __restrict__ knb,
                                                     const unsigned short* __restrict__ ybar,
                                                     const float* __restrict__ rowss,
                                                     const float* __restrict__ kninv,
                                                     const float* __restrict__ anew,
                                                     const int* __restrict__ tlen,
                                                     float* __restrict__ out) {
  const int b = blockIdx.x / 7;
  const int jt = blockIdx.x % 7;
  const int j0 = jt * 16;
  const int len = tlen[b];
  if (j0 >= len) return;                       // rows already zeroed by sem_attn
  const int kbase = min(max(j0 - WPc, 0), Ls - 48);   // 48-window always in-range

  const int tid = threadIdx.x;
  const int wave = tid >> 6, lane = tid & 63;
  const int quad = lane >> 4, l16 = lane & 15;

  __shared__ float red[8][768];   // 24 KB: per-wave partial 16x48 tiles

  const int jj = min(j0 + l16, Ls - 1);        // A-row clamp (tile may overhang L)
  const size_t blj = (size_t)(b * Ls + jj);

  float outacc[3][4];
#pragma unroll
  for (int t = 0; t < 3; ++t)
#pragma unroll
    for (int r = 0; r < 4; ++r) outacc[t][r] = 0.f;

  const unsigned short* yrow[3];
  int krow_m[3];    // flattened GEMM row index base for (k, n=0)
#pragma unroll
  for (int t = 0; t < 3; ++t) {
    const int k = kbase + t * 16 + l16;
    yrow[t] = ybar + (size_t)(b * Ls + k) * Ns * KST;
    krow_m[t] = (b * Ls + k) * Ns;
  }

  for (int ni = 0; ni < 5; ++ni) {
    const int n = wave + ni * 8;
    const unsigned short* __restrict__ arow =
        knb + ((blj * Ns + n) * (size_t)KST) + quad * 8;

    // per-(k,n) weight: issue loads early, math is cheap
    float w_t[3];
#pragma unroll
    for (int t = 0; t < 3; ++t) {
      const int mm = krow_m[t] + n;
      const float a = anew[mm];
      const float ssqk = rowss[mm];
      const float aff = (sqrtf((a - 0.5f) * (a - 0.5f) + 0.25f * a * a) - 0.06467f) *
                        (1.0f / 0.607468f);
      w_t[t] = aff / fmaxf(aff * sqrtf(ssqk), EPSf);
    }
    const float kinv = kninv[blj * Ns + n];   // fp32-accurate 1/||kn(j,n)||

    floatx4 S[3];
#pragma unroll
    for (int t = 0; t < 3; ++t) S[t] = (floatx4){0.f, 0.f, 0.f, 0.f};

#pragma unroll
    for (int c = 0; c < 10; ++c) {
      const short8_t afrag = *reinterpret_cast<const short8_t*>(arow + c * 32);
#pragma unroll
      for (int t = 0; t < 3; ++t) {
        const short8_t bfrag = *reinterpret_cast<const short8_t*>(
            yrow[t] + (size_t)n * KST + c * 32 + quad * 8);
        S[t] = __builtin_amdgcn_mfma_f32_16x16x32_bf16(afrag, bfrag, S[t], 0, 0, 0);
      }
    }

#pragma unroll
    for (int r = 0; r < 4; ++r) {
      const float kv = __shfl(kinv, quad * 4 + r);
#pragma unroll
      for (int t = 0; t < 3; ++t)
        outacc[t][r] = fmaf(kv * w_t[t], fabsf(S[t][r]), outacc[t][r]);
    }
  }

#pragma unroll
  for (int t = 0; t < 3; ++t)
#pragma unroll
    for (int r = 0; r < 4; ++r)
      red[wave][(quad * 4 + r) * 48 + t * 16 + l16] = outacc[t][r];
  __syncthreads();

  for (int idx = tid; idx < 768; idx += 512) {
    float s = 0.f;
#pragma unroll
    for (int w = 0; w < 8; ++w) s += red[w][idx];
    const int j = j0 + idx / 48;
    const int k = kbase + idx % 48;
    if (j < len && k < len && k >= j - WPc && k <= j + WFc)
      out[(size_t)(b * Ls + j) * MAXNc + k] += 5.0f * s;   // 0.5 * 10
  }
}

// ---------------------------------------------------------------------------
extern "C" void kernel_launch(void* const* d_in, const int* in_sizes, int n_in,
                              void* d_out, int out_size, void* d_ws, size_t ws_size,
                              hipStream_t stream) {
  const float* nf   = (const float*)d_in[0];   // (B,L,G)
  const float* kn   = (const float*)d_in[1];   // (B,L,N,D)
  const float* anew = (const float*)d_in[2];   // (B,L,N)
  const float* wsem = (const float*)d_in[3];   // (G,G)
  const float* wcon = (const float*)d_in[4];   // (D,D)
  const int*   tlen = (const int*)d_in[5];     // (B,)
  float* out = (float*)d_out;

  // workspace layout (~190 MB)
  float* att_sem = (float*)d_ws;                            // 3520*512 f32
  float* na_arr  = att_sem + (size_t)BL * Gs;               // 3520 f32
  float* wt      = na_arr + BL;                             // 512*512 f32
  short* wct     = (short*)(wt + (size_t)Gs * Gs);          // 320*320 bf16
  float* rowss   = (float*)(wct + KST * KST);               // Mrows f32
  float* kninv   = rowss + Mrows;                           // Mrows f32
  unsigned short* knb  = (unsigned short*)(kninv + Mrows);  // Mrows*320 bf16
  unsigned short* ybar = knb + (size_t)Mrows * KST;         // Mrows*320 bf16

  hipMemsetAsync(rowss, 0, (size_t)Mrows * sizeof(float), stream);
  transpose_wsem<<<dim3(16, 16), dim3(32, 8), 0, stream>>>(wsem, wt);
  wct_prep<<<dim3(10, 10), dim3(32, 8), 0, stream>>>(wcon, wct);
  kn_prep<<<2048, 256, 0, stream>>>(kn, knb, kninv);
  sem_gemm<<<BL / 8, 512, 0, stream>>>(nf, wt, att_sem, na_arr);
  sem_attn<<<BL, 256, 0, stream>>>(nf, att_sem, na_arr, tlen, out);
  // 2208 = 8 XCDs * 276 slots; g-guard trims the 2 spare groups
  con_gemm_mfma<<<2208, 256, 0, stream>>>(knb, wct, tlen, ybar, rowss);
  con_attn_mfma<<<Bb * 7, 512, 0, stream>>>(knb, ybar, rowss, kninv, anew, tlen, out);
}